// Round 4
// baseline (801.595 us; speedup 1.0000x reference)
//
#include <hip/hip_runtime.h>
#include <stdint.h>

#define D 2048
#define LSEQ 2048
#define BATCH 4
#define BL (BATCH * LSEQ)   // 8192 rows
#define NSLOT 16
#define NHEAD 32
#define HDIM 64
#define EPSV 1e-6f

typedef __attribute__((ext_vector_type(8))) short bf16x8;
typedef __attribute__((ext_vector_type(4))) float f32x4;

static __device__ __forceinline__ ushort f2bf(float f) {
    uint32_t u = __float_as_uint(f);
    u += 0x7fffu + ((u >> 16) & 1u);   // RNE
    return (ushort)(u >> 16);
}

static __device__ __forceinline__ float wave_sum(float v) {
#pragma unroll
    for (int off = 32; off > 0; off >>= 1) v += __shfl_xor(v, off, 64);
    return v;
}

static __device__ __forceinline__ void gl_lds16(const void* g, void* l) {
    __builtin_amdgcn_global_load_lds(
        (__attribute__((address_space(1))) uint32_t*)(uintptr_t)g,
        (__attribute__((address_space(3))) uint32_t*)(uint32_t)(uintptr_t)l,
        16, 0, 0);
}

// ---------------- weight convert f32 -> bf16 ----------------
__global__ __launch_bounds__(256) void conv_bf16_kernel(const float4* __restrict__ src,
                                                        ushort* __restrict__ dst, int n4) {
    int i = blockIdx.x * 256 + threadIdx.x;
    int stride = gridDim.x * 256;
    for (; i < n4; i += stride) {
        float4 v = src[i];
        uint2 o;
        o.x = (uint)f2bf(v.x) | ((uint)f2bf(v.y) << 16);
        o.y = (uint)f2bf(v.z) | ((uint)f2bf(v.w) << 16);
        *(uint2*)(dst + (size_t)i * 4) = o;
    }
}

// ---------------- fused rms + compete logits (+x->bf16) ----------------
__global__ __launch_bounds__(256) void logits_kernel(
    const float* __restrict__ x, const float* __restrict__ cw,
    const float* __restrict__ cb, const float* __restrict__ wpre,
    float* __restrict__ logits_t, ushort* __restrict__ xb, int writeXb) {
    int row = blockIdx.x;              // b*L + l
    int b = row >> 11;
    int l = row & (LSEQ - 1);
    int tid = threadIdx.x;
    const float* xr = x + (size_t)row * D;
    int i0 = tid * 8;
    float4 a0 = *(const float4*)(xr + i0);
    float4 a1 = *(const float4*)(xr + i0 + 4);
    float xv[8] = {a0.x, a0.y, a0.z, a0.w, a1.x, a1.y, a1.z, a1.w};
    if (writeXb) {
        uint4 o;
        o.x = (uint)f2bf(xv[0]) | ((uint)f2bf(xv[1]) << 16);
        o.y = (uint)f2bf(xv[2]) | ((uint)f2bf(xv[3]) << 16);
        o.z = (uint)f2bf(xv[4]) | ((uint)f2bf(xv[5]) << 16);
        o.w = (uint)f2bf(xv[6]) | ((uint)f2bf(xv[7]) << 16);
        *(uint4*)(xb + (size_t)row * D + i0) = o;
    }
    float4 w0 = *(const float4*)(wpre + i0);
    float4 w1 = *(const float4*)(wpre + i0 + 4);
    float wv[8] = {w0.x, w0.y, w0.z, w0.w, w1.x, w1.y, w1.z, w1.w};
    float ss = 0.f;
    float xw[8];
#pragma unroll
    for (int j = 0; j < 8; ++j) { ss += xv[j] * xv[j]; xw[j] = xv[j] * wv[j]; }
    float acc[NSLOT];
#pragma unroll
    for (int s = 0; s < NSLOT; ++s) acc[s] = 0.f;
#pragma unroll
    for (int s = 0; s < NSLOT; ++s) {
        const float* cwr = cw + (size_t)s * D + i0;
        float4 c0 = *(const float4*)(cwr);
        float4 c1 = *(const float4*)(cwr + 4);
        acc[s] = xw[0] * c0.x + xw[1] * c0.y + xw[2] * c0.z + xw[3] * c0.w +
                 xw[4] * c1.x + xw[5] * c1.y + xw[6] * c1.z + xw[7] * c1.w;
    }
    ss = wave_sum(ss);
#pragma unroll
    for (int s = 0; s < NSLOT; ++s) acc[s] = wave_sum(acc[s]);
    __shared__ float red[4][NSLOT];
    __shared__ float redss[4];
    int lane = tid & 63, w = tid >> 6;
    if (lane == 0) {
        redss[w] = ss;
#pragma unroll
        for (int s = 0; s < NSLOT; ++s) red[w][s] = acc[s];
    }
    __syncthreads();
    if (tid < NSLOT) {
        float tot = red[0][tid] + red[1][tid] + red[2][tid] + red[3][tid];
        float s2 = redss[0] + redss[1] + redss[2] + redss[3];
        float rsq = 1.0f / sqrtf(s2 * (1.0f / (float)D) + EPSV);
        logits_t[((size_t)(b * NSLOT + tid)) * LSEQ + l] = tot * rsq + cb[tid];
    }
}

// ---------------- top-4 + softmax + weighted row gather (xbar, bf16) ----------------
__global__ __launch_bounds__(256) void topk_xbar_kernel(
    const float* __restrict__ logits_t, const float* __restrict__ x,
    ushort* __restrict__ xbar_b) {
    int bs = blockIdx.x;
    int b = bs >> 4;
    const float* lr = logits_t + (size_t)bs * LSEQ;
    int tid = threadIdx.x, lane = tid & 63, w = tid >> 6;
    __shared__ float rv[4];
    __shared__ int ri[4];
    __shared__ float selv[4];
    __shared__ int seli[4];
    int i0 = tid * 8;
    float myv[8];
#pragma unroll
    for (int j = 0; j < 8; ++j) myv[j] = lr[i0 + j];
    int chosen[4];
    for (int p = 0; p < 4; ++p) {
        float bv = -3.4e38f;
        int bi = 0x7fffffff;
#pragma unroll
        for (int j = 0; j < 8; ++j) {
            int i = i0 + j;
            bool skip = false;
            for (int q = 0; q < p; ++q) skip = skip || (i == chosen[q]);
            float v = myv[j];
            if (!skip && (v > bv || (v == bv && i < bi))) { bv = v; bi = i; }
        }
#pragma unroll
        for (int off = 1; off < 64; off <<= 1) {
            float ov = __shfl_xor(bv, off, 64);
            int oi = __shfl_xor(bi, off, 64);
            if (ov > bv || (ov == bv && oi < bi)) { bv = ov; bi = oi; }
        }
        if (lane == 0) { rv[w] = bv; ri[w] = bi; }
        __syncthreads();
        if (tid == 0) {
            float fv = rv[0];
            int fi = ri[0];
            for (int q = 1; q < 4; ++q)
                if (rv[q] > fv || (rv[q] == fv && ri[q] < fi)) { fv = rv[q]; fi = ri[q]; }
            selv[p] = fv;
            seli[p] = fi;
        }
        __syncthreads();
        chosen[p] = seli[p];
    }
    float vals[4];
#pragma unroll
    for (int p = 0; p < 4; ++p) vals[p] = selv[p];
    float mx = vals[0];   // first pick is the max
    float e[4], den = 0.f;
#pragma unroll
    for (int p = 0; p < 4; ++p) { e[p] = expf(vals[p] - mx); den += e[p]; }
    float inv = 1.0f / den;
    const float* xr0 = x + ((size_t)b * LSEQ + chosen[0]) * D;
    const float* xr1 = x + ((size_t)b * LSEQ + chosen[1]) * D;
    const float* xr2 = x + ((size_t)b * LSEQ + chosen[2]) * D;
    const float* xr3 = x + ((size_t)b * LSEQ + chosen[3]) * D;
    float s[8];
#pragma unroll
    for (int j = 0; j < 8; ++j) {
        int i = i0 + j;
        s[j] = (e[0] * xr0[i] + e[1] * xr1[i] + e[2] * xr2[i] + e[3] * xr3[i]) * inv;
    }
    uint4 o;
    o.x = (uint)f2bf(s[0]) | ((uint)f2bf(s[1]) << 16);
    o.y = (uint)f2bf(s[2]) | ((uint)f2bf(s[3]) << 16);
    o.z = (uint)f2bf(s[4]) | ((uint)f2bf(s[5]) << 16);
    o.w = (uint)f2bf(s[6]) | ((uint)f2bf(s[7]) << 16);
    *(uint4*)(xbar_b + (size_t)bs * D + i0) = o;
}

// ---------------- ws = rms(ws_prev + written) (+bf16 copy) ----------------
__global__ __launch_bounds__(256) void ws_update_kernel(
    const float* __restrict__ written, const float* __restrict__ ws_prev,
    const float* __restrict__ workspace0, int first,
    const float* __restrict__ wpost, float* __restrict__ ws_out,
    ushort* __restrict__ ws_b) {
    int bs = blockIdx.x;
    int s = bs & (NSLOT - 1);
    int tid = threadIdx.x;
    int i0 = tid * 8;
    const float* prev = first ? (workspace0 + (size_t)s * D) : (ws_prev + (size_t)bs * D);
    const float* wr = written + (size_t)bs * D;
    float4 p0 = *(const float4*)(prev + i0);
    float4 p1 = *(const float4*)(prev + i0 + 4);
    float4 q0 = *(const float4*)(wr + i0);
    float4 q1 = *(const float4*)(wr + i0 + 4);
    float t[8] = {p0.x + q0.x, p0.y + q0.y, p0.z + q0.z, p0.w + q0.w,
                  p1.x + q1.x, p1.y + q1.y, p1.z + q1.z, p1.w + q1.w};
    float ss = 0.f;
#pragma unroll
    for (int j = 0; j < 8; ++j) ss += t[j] * t[j];
    ss = wave_sum(ss);
    __shared__ float sb[4];
    if ((tid & 63) == 0) sb[tid >> 6] = ss;
    __syncthreads();
    ss = sb[0] + sb[1] + sb[2] + sb[3];
    float rsq = 1.0f / sqrtf(ss * (1.0f / (float)D) + EPSV);
    float4 w0 = *(const float4*)(wpost + i0);
    float4 w1 = *(const float4*)(wpost + i0 + 4);
    float wv[8] = {w0.x, w0.y, w0.z, w0.w, w1.x, w1.y, w1.z, w1.w};
    float o[8];
#pragma unroll
    for (int j = 0; j < 8; ++j) o[j] = t[j] * rsq * wv[j];
    float4 r0 = {o[0], o[1], o[2], o[3]};
    float4 r1 = {o[4], o[5], o[6], o[7]};
    *(float4*)(ws_out + (size_t)bs * D + i0) = r0;
    *(float4*)(ws_out + (size_t)bs * D + i0 + 4) = r1;
    uint4 ob;
    ob.x = (uint)f2bf(o[0]) | ((uint)f2bf(o[1]) << 16);
    ob.y = (uint)f2bf(o[2]) | ((uint)f2bf(o[3]) << 16);
    ob.z = (uint)f2bf(o[4]) | ((uint)f2bf(o[5]) << 16);
    ob.w = (uint)f2bf(o[6]) | ((uint)f2bf(o[7]) << 16);
    *(uint4*)(ws_b + (size_t)bs * D + i0) = ob;
}

// ---------------- x = rms(x + attn_out) (+bf16 copy) ----------------
__global__ __launch_bounds__(256) void resid_rms_kernel(
    const float* __restrict__ x_src, const float* __restrict__ ao,
    const float* __restrict__ wpost, float* __restrict__ x_dst,
    ushort* __restrict__ xb) {
    int row = blockIdx.x;
    int tid = threadIdx.x;
    int i0 = tid * 8;
    const float* xr = x_src + (size_t)row * D;
    const float* ar = ao + (size_t)row * D;
    float4 p0 = *(const float4*)(xr + i0);
    float4 p1 = *(const float4*)(xr + i0 + 4);
    float4 q0 = *(const float4*)(ar + i0);
    float4 q1 = *(const float4*)(ar + i0 + 4);
    float t[8] = {p0.x + q0.x, p0.y + q0.y, p0.z + q0.z, p0.w + q0.w,
                  p1.x + q1.x, p1.y + q1.y, p1.z + q1.z, p1.w + q1.w};
    float ss = 0.f;
#pragma unroll
    for (int j = 0; j < 8; ++j) ss += t[j] * t[j];
    ss = wave_sum(ss);
    __shared__ float sb[4];
    if ((tid & 63) == 0) sb[tid >> 6] = ss;
    __syncthreads();
    ss = sb[0] + sb[1] + sb[2] + sb[3];
    float rsq = 1.0f / sqrtf(ss * (1.0f / (float)D) + EPSV);
    float4 w0 = *(const float4*)(wpost + i0);
    float4 w1 = *(const float4*)(wpost + i0 + 4);
    float wv[8] = {w0.x, w0.y, w0.z, w0.w, w1.x, w1.y, w1.z, w1.w};
    float o[8];
#pragma unroll
    for (int j = 0; j < 8; ++j) o[j] = t[j] * rsq * wv[j];
    float4 r0 = {o[0], o[1], o[2], o[3]};
    float4 r1 = {o[4], o[5], o[6], o[7]};
    *(float4*)(x_dst + (size_t)row * D + i0) = r0;
    *(float4*)(x_dst + (size_t)row * D + i0 + 4) = r1;
    uint4 ob;
    ob.x = (uint)f2bf(o[0]) | ((uint)f2bf(o[1]) << 16);
    ob.y = (uint)f2bf(o[2]) | ((uint)f2bf(o[3]) << 16);
    ob.z = (uint)f2bf(o[4]) | ((uint)f2bf(o[5]) << 16);
    ob.w = (uint)f2bf(o[6]) | ((uint)f2bf(o[7]) << 16);
    *(uint4*)(xb + (size_t)row * D + i0) = ob;
}

// ---------------- attention v3: 128-row tiles, 128 threads, 20KB LDS ----------------
// 8 blocks/CU (vs 4) -> 2x occupancy for latency hiding. q read as bf16 (written
// by gemm_big<ushort>), staged via async gl_lds16 with pre-swizzled source
// (chunk ^ row&7, rule #21). ctx written coalesced via LDS bounce (full lines).
__global__ __launch_bounds__(128) void attn_kernel(
    const ushort* __restrict__ qb, const float* __restrict__ kv,
    ushort* __restrict__ ctxb) {
    __shared__ ushort qlds[128 * 64];   // 16 KB (q, then reused for ctx bounce)
    __shared__ ushort klds[16 * 64];    // 2 KB
    __shared__ ushort vlds[16 * 64];    // 2 KB
    int blk = blockIdx.x;
    int b  = blk >> 9;                  // 32 h * 16 ltiles = 512 blocks per batch
    int h  = (blk >> 4) & 31;
    int l0 = (blk & 15) << 7;
    int tid = threadIdx.x;
    int lane = tid & 63, wvi = tid >> 6;
    // async-stage q tile (128 rows x 128B), pre-swizzled global source
    const ushort* qbase = qb + ((size_t)b * LSEQ + l0) * D + h * HDIM;
#pragma unroll
    for (int p = 0; p < 8; ++p) {
        int cb = p * 128 + wvi * 64;    // wave-uniform chunk base
        int ch = cb + lane;
        int r = ch >> 3;
        int c = (ch & 7) ^ (r & 7);
        gl_lds16(qbase + (size_t)r * D + c * 8, (void*)((char*)qlds + cb * 16));
    }
    // reg-stage K,V as bf16 (linear; compute reads are wave-uniform broadcasts)
    {
        int s = tid >> 3;
        int d8 = (tid & 7) * 8;
        const float* kp = kv + ((size_t)(b * NSLOT + s)) * (2 * D) + h * HDIM + d8;
        float4 k0 = *(const float4*)kp;
        float4 k1 = *(const float4*)(kp + 4);
        float4 v0 = *(const float4*)(kp + D);
        float4 v1 = *(const float4*)(kp + D + 4);
        uint4 ko, vo;
        ko.x = (uint)f2bf(k0.x) | ((uint)f2bf(k0.y) << 16);
        ko.y = (uint)f2bf(k0.z) | ((uint)f2bf(k0.w) << 16);
        ko.z = (uint)f2bf(k1.x) | ((uint)f2bf(k1.y) << 16);
        ko.w = (uint)f2bf(k1.z) | ((uint)f2bf(k1.w) << 16);
        vo.x = (uint)f2bf(v0.x) | ((uint)f2bf(v0.y) << 16);
        vo.y = (uint)f2bf(v0.z) | ((uint)f2bf(v0.w) << 16);
        vo.z = (uint)f2bf(v1.x) | ((uint)f2bf(v1.y) << 16);
        vo.w = (uint)f2bf(v1.z) | ((uint)f2bf(v1.w) << 16);
        *(uint4*)&klds[s * 64 + d8] = ko;
        *(uint4*)&vlds[s * 64 + d8] = vo;
    }
    __syncthreads();                    // drains gl_lds16 (vmcnt) + ds_writes
    int r = tid;                        // this thread's row (0..127)
    float acc[NSLOT];
#pragma unroll
    for (int s = 0; s < NSLOT; ++s) acc[s] = 0.f;
#pragma unroll
    for (int dc = 0; dc < 8; ++dc) {
        uint4 qc = *(const uint4*)&qlds[r * 64 + ((dc ^ (r & 7)) << 3)];
        float qf[8];
        qf[0] = __uint_as_float(qc.x << 16);
        qf[1] = __uint_as_float(qc.x & 0xffff0000u);
        qf[2] = __uint_as_float(qc.y << 16);
        qf[3] = __uint_as_float(qc.y & 0xffff0000u);
        qf[4] = __uint_as_float(qc.z << 16);
        qf[5] = __uint_as_float(qc.z & 0xffff0000u);
        qf[6] = __uint_as_float(qc.w << 16);
        qf[7] = __uint_as_float(qc.w & 0xffff0000u);
#pragma unroll
        for (int s = 0; s < NSLOT; ++s) {
            uint4 kc = *(const uint4*)&klds[s * 64 + dc * 8];   // broadcast
            float a = acc[s];
            a += qf[0] * __uint_as_float(kc.x << 16);
            a += qf[1] * __uint_as_float(kc.x & 0xffff0000u);
            a += qf[2] * __uint_as_float(kc.y << 16);
            a += qf[3] * __uint_as_float(kc.y & 0xffff0000u);
            a += qf[4] * __uint_as_float(kc.z << 16);
            a += qf[5] * __uint_as_float(kc.z & 0xffff0000u);
            a += qf[6] * __uint_as_float(kc.w << 16);
            a += qf[7] * __uint_as_float(kc.w & 0xffff0000u);
            acc[s] = a;
        }
    }
    float mx = acc[0];
#pragma unroll
    for (int s = 1; s < NSLOT; ++s) mx = fmaxf(mx, acc[s]);
    float e[NSLOT], den = 0.f;
#pragma unroll
    for (int s = 0; s < NSLOT; ++s) { e[s] = __expf((acc[s] - mx) * 0.125f); den += e[s]; }
    float inv = 1.0f / den;
#pragma unroll
    for (int s = 0; s < NSLOT; ++s) e[s] *= inv;
    // PV: write own-row ctx bf16 into qlds (own slots only -> no barrier needed yet)
#pragma unroll
    for (int dc = 0; dc < 8; ++dc) {
        float cx[8] = {0.f, 0.f, 0.f, 0.f, 0.f, 0.f, 0.f, 0.f};
#pragma unroll
        for (int s = 0; s < NSLOT; ++s) {
            uint4 vc = *(const uint4*)&vlds[s * 64 + dc * 8];   // broadcast
            float es = e[s];
            cx[0] += es * __uint_as_float(vc.x << 16);
            cx[1] += es * __uint_as_float(vc.x & 0xffff0000u);
            cx[2] += es * __uint_as_float(vc.y << 16);
            cx[3] += es * __uint_as_float(vc.y & 0xffff0000u);
            cx[4] += es * __uint_as_float(vc.z << 16);
            cx[5] += es * __uint_as_float(vc.z & 0xffff0000u);
            cx[6] += es * __uint_as_float(vc.w << 16);
            cx[7] += es * __uint_as_float(vc.w & 0xffff0000u);
        }
        uint4 o;
        o.x = (uint)f2bf(cx[0]) | ((uint)f2bf(cx[1]) << 16);
        o.y = (uint)f2bf(cx[2]) | ((uint)f2bf(cx[3]) << 16);
        o.z = (uint)f2bf(cx[4]) | ((uint)f2bf(cx[5]) << 16);
        o.w = (uint)f2bf(cx[6]) | ((uint)f2bf(cx[7]) << 16);
        *(uint4*)&qlds[r * 64 + dc * 8] = o;    // linear (q fully consumed)
    }
    __syncthreads();
    // cooperative coalesced global write: 128B per row = 2 full 64B lines
    ushort* cbase = ctxb + ((size_t)b * LSEQ + l0) * D + h * HDIM;
#pragma unroll
    for (int p = 0; p < 8; ++p) {
        int cid = p * 128 + tid;
        int row = cid >> 3;
        int c = cid & 7;
        *(uint4*)(cbase + (size_t)row * D + c * 8) = *(const uint4*)&qlds[row * 64 + c * 8];
    }
}

// ---------------- small-M bf16 MFMA GEMM (M<=128 rows) ----------------
template <int BM>
__global__ __launch_bounds__(256) void gemm_bt(
    const ushort* __restrict__ A, const ushort* __restrict__ Bw,
    const float* __restrict__ bias, float* __restrict__ C,
    int M, int N, int K) {
    constexpr int BN = 128, BK = 32;
    constexpr int MF = BM / 32;
    constexpr int APASS = (BM * BK / 8) / 256;
    __shared__ short lds[2][(BM + BN) * BK];
    int tid = threadIdx.x;
    int lane = tid & 63, w = tid >> 6;
    int wr = w >> 1, wc = w & 1;
    int tn = blockIdx.x * BN;
    int tm = blockIdx.y * BM;
    f32x4 acc[MF][4];
    f32x4 zero = {0.f, 0.f, 0.f, 0.f};
#pragma unroll
    for (int m = 0; m < MF; ++m)
#pragma unroll
        for (int n = 0; n < 4; ++n) acc[m][n] = zero;
    int NT = K / BK;

    auto stage = [&](int buf, int t) {
        int kt = t * BK;
#pragma unroll
        for (int p = 0; p < APASS; ++p) {
            int cb = p * 256 + w * 64;
            int c = cb + lane;
            int r = c >> 2;
            int k8 = (c & 3) * 8;
            int gr = tm + r;
            if (gr >= M) gr = M - 1;
            gl_lds16(A + (size_t)gr * K + kt + k8, (void*)&lds[buf][cb * 8]);
        }
#pragma unroll
        for (int p = 0; p < 2; ++p) {
            int cb = p * 256 + w * 64;
            int c = cb + lane;
            int r = c >> 2;
            int k8 = (c & 3) * 8;
            gl_lds16(Bw + (size_t)(tn + r) * K + kt + k8,
                     (void*)&lds[buf][BM * BK + cb * 8]);
        }
    };
    stage(0, 0);
    for (int t = 0; t < NT; ++t) {
        __syncthreads();
        if (t + 1 < NT) stage((t + 1) & 1, t + 1);
        const short* Ab = &lds[t & 1][0];
        const short* Bb = &lds[t & 1][BM * BK];
        int ko = (lane >> 4) * 8;
        int rr = lane & 15;
        bf16x8 af[MF], bfr[4];
#pragma unroll
        for (int m = 0; m < MF; ++m)
            af[m] = *(const bf16x8*)&Ab[(wr * (MF * 16) + m * 16 + rr) * BK + ko];
#pragma unroll
        for (int n = 0; n < 4; ++n)
            bfr[n] = *(const bf16x8*)&Bb[(wc * 64 + n * 16 + rr) * BK + ko];
#pragma unroll
        for (int m = 0; m < MF; ++m)
#pragma unroll
            for (int n = 0; n < 4; ++n)
                acc[m][n] = __builtin_amdgcn_mfma_f32_16x16x32_bf16(af[m], bfr[n],
                                                                    acc[m][n], 0, 0, 0);
    }
#pragma unroll
    for (int m = 0; m < MF; ++m) {
#pragma unroll
        for (int n = 0; n < 4; ++n) {
            int col = tn + wc * 64 + n * 16 + (lane & 15);
            float bsv = bias ? bias[col] : 0.f;
#pragma unroll
            for (int r = 0; r < 4; ++r) {
                int rowi = tm + wr * (MF * 16) + m * 16 + (lane >> 4) * 4 + r;
                if (rowi < M) C[(size_t)rowi * N + col] = acc[m][n][r] + bsv;
            }
        }
    }
}

// ---------------- big GEMM: 256x256 tile, BK=64, 8 waves, counted vmcnt ----------------
// OT = float (full precision out) or ushort (bf16 out, halves write traffic).
template <typename OT>
__global__ __launch_bounds__(512, 2) void gemm_big(
    const ushort* __restrict__ A, const ushort* __restrict__ Bw,
    const float* __restrict__ bias, OT* __restrict__ C,
    int M, int N, int K) {
    __shared__ ushort Al[2][256 * 64];   // 64 KiB
    __shared__ ushort Bl[2][256 * 64];   // 64 KiB
    int blk = blockIdx.x;
    int bn = blk & 7;                    // same-XCD blocks share B panel (L2)
    int bm = blk >> 3;
    int tid = threadIdx.x;
    int lane = tid & 63, wv = tid >> 6;
    int wm = wv >> 2, wn = wv & 3;       // 2 x 4 wave grid -> 128x64 per wave
    int rr = lane & 15, ko = lane >> 4;  // frag row, k-octet 0..3
    const size_t rowA0 = (size_t)bm * 256;
    const size_t rowB0 = (size_t)bn * 256;

    auto stage = [&](int buf, int t) {
        int kt = t * 64;
#pragma unroll
        for (int p = 0; p < 4; ++p) {
            int cb = p * 512 + wv * 64;          // wave-uniform chunk base
            int ch = cb + lane;
            int r = ch >> 3;
            int cl = (ch & 7) ^ (r & 7);         // pre-swizzled source chunk
            gl_lds16(A + (rowA0 + r) * K + kt + cl * 8,
                     (void*)((char*)&Al[buf][0] + cb * 16));
        }
#pragma unroll
        for (int p = 0; p < 4; ++p) {
            int cb = p * 512 + wv * 64;
            int ch = cb + lane;
            int r = ch >> 3;
            int cl = (ch & 7) ^ (r & 7);
            gl_lds16(Bw + (rowB0 + r) * K + kt + cl * 8,
                     (void*)((char*)&Bl[buf][0] + cb * 16));
        }
    };

    f32x4 acc[8][4];
    f32x4 zero = {0.f, 0.f, 0.f, 0.f};
#pragma unroll
    for (int m = 0; m < 8; ++m)
#pragma unroll
        for (int n = 0; n < 4; ++n) acc[m][n] = zero;

    int NT = K / 64;
    stage(0, 0);
    stage(1, 1);
    for (int t = 0; t < NT; ++t) {
        // wait for THIS tile's 8 loads (t+1's 8 may stay in flight)
        if (t + 2 <= NT) asm volatile("s_waitcnt vmcnt(8)" ::: "memory");
        else             asm volatile("s_waitcnt vmcnt(0)" ::: "memory");
        asm volatile("s_barrier" ::: "memory");   // all waves' tile-t loads landed
        const ushort* Ab = &Al[t & 1][0];
        const ushort* Bb = &Bl[t & 1][0];
        bf16x8 bfr[4][2];
#pragma unroll
        for (int n = 0; n < 4; ++n)
#pragma unroll
            for (int ks = 0; ks < 2; ++ks) {
                int r = wn * 64 + n * 16 + rr;
                int cl = ks * 4 + ko;
                bfr[n][ks] = *(const bf16x8*)((const char*)Bb + r * 128 +
                                              ((cl ^ (r & 7)) * 16));
            }
        __builtin_amdgcn_s_setprio(1);
#pragma unroll
        for (int m = 0; m < 8; ++m) {
            int r = wm * 128 + m * 16 + rr;
            bf16x8 a0 = *(const bf16x8*)((const char*)Ab + r * 128 +
                                         (((0 + ko) ^ (r & 7)) * 16));
            bf16x8 a1 = *(const bf16x8*)((const char*)Ab + r * 128 +
                                         (((4 + ko) ^ (r & 7)) * 16));
#pragma unroll
            for (int n = 0; n < 4; ++n) {
                acc[m][n] = __builtin_amdgcn_mfma_f32_16x16x32_bf16(a0, bfr[n][0],
                                                                    acc[m][n], 0, 0, 0);
                acc[m][n] = __builtin_amdgcn_mfma_f32_16x16x32_bf16(a1, bfr[n][1],
                                                                    acc[m][n], 0, 0, 0);
            }
        }
        __builtin_amdgcn_s_setprio(0);
        asm volatile("s_barrier" ::: "memory");   // all waves done reading buf[t&1]
        if (t + 2 < NT) stage(t & 1, t + 2);      // overwrite just-consumed buffer
    }
    int crow0 = (int)rowA0 + wm * 128;
    int ccol0 = bn * 256 + wn * 64;
#pragma unroll
    for (int m = 0; m < 8; ++m)
#pragma unroll
        for (int n = 0; n < 4; ++n) {
            int col = ccol0 + n * 16 + rr;
            float bsv = bias ? bias[col] : 0.f;
#pragma unroll
            for (int r4 = 0; r4 < 4; ++r4) {
                int row = crow0 + m * 16 + ko * 4 + r4;
                float v = acc[m][n][r4] + bsv;
                if constexpr (sizeof(OT) == 2) {
                    ((ushort*)C)[(size_t)row * N + col] = f2bf(v);
                } else {
                    ((float*)C)[(size_t)row * N + col] = v;
                }
            }
        }
}

extern "C" void kernel_launch(void* const* d_in, const int* in_sizes, int n_in,
                              void* d_out, int out_size, void* d_ws, size_t ws_size,
                              hipStream_t stream) {
    const float* x_in       = (const float*)d_in[0];
    const float* workspace  = (const float*)d_in[1];
    const float* compete_w  = (const float*)d_in[2];
    const float* compete_b  = (const float*)d_in[3];
    const float* write_w    = (const float*)d_in[4];
    const float* write_b    = (const float*)d_in[5];
    const float* in_proj_w  = (const float*)d_in[6];
    const float* in_proj_b  = (const float*)d_in[7];
    const float* out_proj_w = (const float*)d_in[8];
    const float* out_proj_b = (const float*)d_in[9];
    const float* norm_pre_w  = (const float*)d_in[12];
    const float* norm_post_w = (const float*)d_in[13];
    float* xout = (float*)d_out;

    char* base = (char*)d_ws;
    size_t off = 0;
    auto alloc = [&](size_t bytes) {
        void* p = base + off;
        off += (bytes + 255) & ~(size_t)255;
        return p;
    };
    ushort* xb      = (ushort*)alloc((size_t)BL * D * 2);
    float*  qbuf    = (float*) alloc((size_t)BL * D * 4);     // attn_out (f32)
    ushort* qbb     = (ushort*)alloc((size_t)BL * D * 2);     // q bf16
    ushort* ctxb    = (ushort*)alloc((size_t)BL * D * 2);
    float*  logits  = (float*) alloc((size_t)BATCH * NSLOT * LSEQ * 4);
    ushort* xbar    = (ushort*)alloc((size_t)BATCH * NSLOT * D * 2);
    float*  written = (float*) alloc((size_t)BATCH * NSLOT * D * 4);
    float*  wsbuf   = (float*) alloc((size_t)BATCH * NSLOT * D * 4);
    ushort* wsb     = (ushort*)alloc((size_t)BATCH * NSLOT * D * 2);
    float*  kvbuf   = (float*) alloc((size_t)BATCH * NSLOT * 2 * D * 4);
    ushort* ipb     = (ushort*)alloc((size_t)3 * D * D * 2);
    ushort* wob     = (ushort*)alloc((size_t)D * D * 2);
    ushort* wwb     = (ushort*)alloc((size_t)D * D * 2);
    (void)ws_size; (void)in_sizes; (void)n_in; (void)out_size;

    conv_bf16_kernel<<<2048, 256, 0, stream>>>((const float4*)in_proj_w, ipb, 3 * D * D / 4);
    conv_bf16_kernel<<<2048, 256, 0, stream>>>((const float4*)out_proj_w, wob, D * D / 4);
    conv_bf16_kernel<<<2048, 256, 0, stream>>>((const float4*)write_w, wwb, D * D / 4);

    for (int it = 0; it < 2; ++it) {
        const float* xs = it ? (const float*)xout : x_in;
        logits_kernel<<<BL, 256, 0, stream>>>(xs, compete_w, compete_b, norm_pre_w,
                                              logits, xb, it == 0 ? 1 : 0);
        topk_xbar_kernel<<<BATCH * NSLOT, 256, 0, stream>>>(logits, xs, xbar);
        gemm_bt<64><<<dim3(D / 128, 1), 256, 0, stream>>>(xbar, wwb, write_b, written,
                                                          BATCH * NSLOT, D, D);
        ws_update_kernel<<<BATCH * NSLOT, 256, 0, stream>>>(written, wsbuf, workspace,
                                                            it == 0 ? 1 : 0, norm_post_w,
                                                            wsbuf, wsb);
        gemm_bt<64><<<dim3(2 * D / 128, 1), 256, 0, stream>>>(wsb, ipb + (size_t)D * D,
                                                              in_proj_b + D, kvbuf,
                                                              BATCH * NSLOT, 2 * D, D);
        gemm_big<ushort><<<(D / 256) * (BL / 256), 512, 0, stream>>>(xb, ipb, in_proj_b,
                                                                     qbb, BL, D, D);
        attn_kernel<<<BATCH * NHEAD * (LSEQ / 128), 128, 0, stream>>>(qbb, kvbuf, ctxb);
        gemm_big<float><<<(D / 256) * (BL / 256), 512, 0, stream>>>(ctxb, wob, out_proj_b,
                                                                    qbuf, BL, D, D);
        resid_rms_kernel<<<BL, 256, 0, stream>>>(xs, qbuf, norm_post_w, xout, xb);
    }
}

// Round 6
// 772.886 us; speedup vs baseline: 1.0371x; 1.0371x over previous
//
#include <hip/hip_runtime.h>
#include <stdint.h>

#define D 2048
#define LSEQ 2048
#define BATCH 4
#define BL (BATCH * LSEQ)   // 8192 rows
#define NSLOT 16
#define NHEAD 32
#define HDIM 64
#define EPSV 1e-6f

typedef __attribute__((ext_vector_type(8))) short bf16x8;
typedef __attribute__((ext_vector_type(4))) float f32x4;

static __device__ __forceinline__ ushort f2bf(float f) {
    uint32_t u = __float_as_uint(f);
    u += 0x7fffu + ((u >> 16) & 1u);   // RNE
    return (ushort)(u >> 16);
}

static __device__ __forceinline__ float wave_sum(float v) {
#pragma unroll
    for (int off = 32; off > 0; off >>= 1) v += __shfl_xor(v, off, 64);
    return v;
}

static __device__ __forceinline__ void gl_lds16(const void* g, void* l) {
    __builtin_amdgcn_global_load_lds(
        (__attribute__((address_space(1))) uint32_t*)(uintptr_t)g,
        (__attribute__((address_space(3))) uint32_t*)(uint32_t)(uintptr_t)l,
        16, 0, 0);
}

// ---------------- weight convert f32 -> bf16 ----------------
__global__ __launch_bounds__(256) void conv_bf16_kernel(const float4* __restrict__ src,
                                                        ushort* __restrict__ dst, int n4) {
    int i = blockIdx.x * 256 + threadIdx.x;
    int stride = gridDim.x * 256;
    for (; i < n4; i += stride) {
        float4 v = src[i];
        uint2 o;
        o.x = (uint)f2bf(v.x) | ((uint)f2bf(v.y) << 16);
        o.y = (uint)f2bf(v.z) | ((uint)f2bf(v.w) << 16);
        *(uint2*)(dst + (size_t)i * 4) = o;
    }
}

// ---------------- logits v4: 4 rows/block, BIT-EXACT to the R4-passing kernel ----
// Per-row computation (xw partials, wave_sum tree, cross-wave add order, rsq, fma)
// matches the R4 kernel lane-for-lane, so logits bits — and thus top-k — are
// identical to the passing run. Speedup comes from amortizing the 128KB cw read
// over 4 rows per block (the R4 cost was data movement, not the shuffles).
__global__ __launch_bounds__(256) void logits_kernel(
    const float* __restrict__ x, const float* __restrict__ cw,
    const float* __restrict__ cb, const float* __restrict__ wpre,
    float* __restrict__ logits_t) {
    int blk = blockIdx.x;              // 2048 blocks, 4 rows each
    int b = blk >> 9;                  // 512 blocks per batch
    int l0 = (blk & 511) << 2;
    int tid = threadIdx.x;
    int i0 = tid * 8;
    float4 w0 = *(const float4*)(wpre + i0);
    float4 w1 = *(const float4*)(wpre + i0 + 4);
    float wv[8] = {w0.x, w0.y, w0.z, w0.w, w1.x, w1.y, w1.z, w1.w};
    float xw[4][8];
    float ss[4];
#pragma unroll
    for (int r = 0; r < 4; ++r) {
        const float* xr = x + ((size_t)(b * LSEQ + l0 + r)) * D;
        float4 a0 = *(const float4*)(xr + i0);
        float4 a1 = *(const float4*)(xr + i0 + 4);
        float xv[8] = {a0.x, a0.y, a0.z, a0.w, a1.x, a1.y, a1.z, a1.w};
        float s0 = 0.f;
#pragma unroll
        for (int j = 0; j < 8; ++j) { s0 += xv[j] * xv[j]; xw[r][j] = xv[j] * wv[j]; }
        ss[r] = s0;
    }
    float acc[NSLOT][4];
#pragma unroll
    for (int s = 0; s < NSLOT; ++s) {
        const float* cwr = cw + (size_t)s * D + i0;
        float4 c0 = *(const float4*)(cwr);
        float4 c1 = *(const float4*)(cwr + 4);
#pragma unroll
        for (int r = 0; r < 4; ++r)
            acc[s][r] = xw[r][0] * c0.x + xw[r][1] * c0.y + xw[r][2] * c0.z + xw[r][3] * c0.w +
                        xw[r][4] * c1.x + xw[r][5] * c1.y + xw[r][6] * c1.z + xw[r][7] * c1.w;
    }
#pragma unroll
    for (int r = 0; r < 4; ++r) ss[r] = wave_sum(ss[r]);
#pragma unroll
    for (int s = 0; s < NSLOT; ++s)
#pragma unroll
        for (int r = 0; r < 4; ++r) acc[s][r] = wave_sum(acc[s][r]);
    __shared__ float red[4][NSLOT][4];
    __shared__ float redss[4][4];
    int lane = tid & 63, w = tid >> 6;
    if (lane == 0) {
#pragma unroll
        for (int r = 0; r < 4; ++r) redss[w][r] = ss[r];
#pragma unroll
        for (int s = 0; s < NSLOT; ++s)
#pragma unroll
            for (int r = 0; r < 4; ++r) red[w][s][r] = acc[s][r];
    }
    __syncthreads();
    if (tid < 64) {
        int s = tid >> 2, r = tid & 3;
        float tot = red[0][s][r] + red[1][s][r] + red[2][s][r] + red[3][s][r];
        float s2 = redss[0][r] + redss[1][r] + redss[2][r] + redss[3][r];
        float rsq = 1.0f / sqrtf(s2 * (1.0f / (float)D) + EPSV);
        logits_t[((size_t)(b * NSLOT + s)) * LSEQ + l0 + r] = tot * rsq + cb[s];
    }
}

// ---------------- top-4 + softmax + weighted row gather (xbar, bf16) ----------------
__global__ __launch_bounds__(256) void topk_xbar_kernel(
    const float* __restrict__ logits_t, const float* __restrict__ x,
    ushort* __restrict__ xbar_b) {
    int bs = blockIdx.x;
    int b = bs >> 4;
    const float* lr = logits_t + (size_t)bs * LSEQ;
    int tid = threadIdx.x, lane = tid & 63, w = tid >> 6;
    __shared__ float rv[4];
    __shared__ int ri[4];
    __shared__ float selv[4];
    __shared__ int seli[4];
    int i0 = tid * 8;
    float myv[8];
#pragma unroll
    for (int j = 0; j < 8; ++j) myv[j] = lr[i0 + j];
    int chosen[4];
    for (int p = 0; p < 4; ++p) {
        float bv = -3.4e38f;
        int bi = 0x7fffffff;
#pragma unroll
        for (int j = 0; j < 8; ++j) {
            int i = i0 + j;
            bool skip = false;
            for (int q = 0; q < p; ++q) skip = skip || (i == chosen[q]);
            float v = myv[j];
            if (!skip && (v > bv || (v == bv && i < bi))) { bv = v; bi = i; }
        }
#pragma unroll
        for (int off = 1; off < 64; off <<= 1) {
            float ov = __shfl_xor(bv, off, 64);
            int oi = __shfl_xor(bi, off, 64);
            if (ov > bv || (ov == bv && oi < bi)) { bv = ov; bi = oi; }
        }
        if (lane == 0) { rv[w] = bv; ri[w] = bi; }
        __syncthreads();
        if (tid == 0) {
            float fv = rv[0];
            int fi = ri[0];
            for (int q = 1; q < 4; ++q)
                if (rv[q] > fv || (rv[q] == fv && ri[q] < fi)) { fv = rv[q]; fi = ri[q]; }
            selv[p] = fv;
            seli[p] = fi;
        }
        __syncthreads();
        chosen[p] = seli[p];
    }
    float vals[4];
#pragma unroll
    for (int p = 0; p < 4; ++p) vals[p] = selv[p];
    float mx = vals[0];   // first pick is the max
    float e[4], den = 0.f;
#pragma unroll
    for (int p = 0; p < 4; ++p) { e[p] = expf(vals[p] - mx); den += e[p]; }
    float inv = 1.0f / den;
    const float* xr0 = x + ((size_t)b * LSEQ + chosen[0]) * D;
    const float* xr1 = x + ((size_t)b * LSEQ + chosen[1]) * D;
    const float* xr2 = x + ((size_t)b * LSEQ + chosen[2]) * D;
    const float* xr3 = x + ((size_t)b * LSEQ + chosen[3]) * D;
    float s[8];
#pragma unroll
    for (int j = 0; j < 8; ++j) {
        int i = i0 + j;
        s[j] = (e[0] * xr0[i] + e[1] * xr1[i] + e[2] * xr2[i] + e[3] * xr3[i]) * inv;
    }
    uint4 o;
    o.x = (uint)f2bf(s[0]) | ((uint)f2bf(s[1]) << 16);
    o.y = (uint)f2bf(s[2]) | ((uint)f2bf(s[3]) << 16);
    o.z = (uint)f2bf(s[4]) | ((uint)f2bf(s[5]) << 16);
    o.w = (uint)f2bf(s[6]) | ((uint)f2bf(s[7]) << 16);
    *(uint4*)(xbar_b + (size_t)bs * D + i0) = o;
}

// ---------------- ws = rms(ws_prev + written) (+bf16 copy) ----------------
__global__ __launch_bounds__(256) void ws_update_kernel(
    const float* __restrict__ written, const float* __restrict__ ws_prev,
    const float* __restrict__ workspace0, int first,
    const float* __restrict__ wpost, float* __restrict__ ws_out,
    ushort* __restrict__ ws_b) {
    int bs = blockIdx.x;
    int s = bs & (NSLOT - 1);
    int tid = threadIdx.x;
    int i0 = tid * 8;
    const float* prev = first ? (workspace0 + (size_t)s * D) : (ws_prev + (size_t)bs * D);
    const float* wr = written + (size_t)bs * D;
    float4 p0 = *(const float4*)(prev + i0);
    float4 p1 = *(const float4*)(prev + i0 + 4);
    float4 q0 = *(const float4*)(wr + i0);
    float4 q1 = *(const float4*)(wr + i0 + 4);
    float t[8] = {p0.x + q0.x, p0.y + q0.y, p0.z + q0.z, p0.w + q0.w,
                  p1.x + q1.x, p1.y + q1.y, p1.z + q1.z, p1.w + q1.w};
    float ss = 0.f;
#pragma unroll
    for (int j = 0; j < 8; ++j) ss += t[j] * t[j];
    ss = wave_sum(ss);
    __shared__ float sb[4];
    if ((tid & 63) == 0) sb[tid >> 6] = ss;
    __syncthreads();
    ss = sb[0] + sb[1] + sb[2] + sb[3];
    float rsq = 1.0f / sqrtf(ss * (1.0f / (float)D) + EPSV);
    float4 w0 = *(const float4*)(wpost + i0);
    float4 w1 = *(const float4*)(wpost + i0 + 4);
    float wv[8] = {w0.x, w0.y, w0.z, w0.w, w1.x, w1.y, w1.z, w1.w};
    float o[8];
#pragma unroll
    for (int j = 0; j < 8; ++j) o[j] = t[j] * rsq * wv[j];
    float4 r0 = {o[0], o[1], o[2], o[3]};
    float4 r1 = {o[4], o[5], o[6], o[7]};
    *(float4*)(ws_out + (size_t)bs * D + i0) = r0;
    *(float4*)(ws_out + (size_t)bs * D + i0 + 4) = r1;
    uint4 ob;
    ob.x = (uint)f2bf(o[0]) | ((uint)f2bf(o[1]) << 16);
    ob.y = (uint)f2bf(o[2]) | ((uint)f2bf(o[3]) << 16);
    ob.z = (uint)f2bf(o[4]) | ((uint)f2bf(o[5]) << 16);
    ob.w = (uint)f2bf(o[6]) | ((uint)f2bf(o[7]) << 16);
    *(uint4*)(ws_b + (size_t)bs * D + i0) = ob;
}

// ---------------- x = rms(x + attn_out) (+bf16 copy) ----------------
__global__ __launch_bounds__(256) void resid_rms_kernel(
    const float* __restrict__ x_src, const float* __restrict__ ao,
    const float* __restrict__ wpost, float* __restrict__ x_dst,
    ushort* __restrict__ xb) {
    int row = blockIdx.x;
    int tid = threadIdx.x;
    int i0 = tid * 8;
    const float* xr = x_src + (size_t)row * D;
    const float* ar = ao + (size_t)row * D;
    float4 p0 = *(const float4*)(xr + i0);
    float4 p1 = *(const float4*)(xr + i0 + 4);
    float4 q0 = *(const float4*)(ar + i0);
    float4 q1 = *(const float4*)(ar + i0 + 4);
    float t[8] = {p0.x + q0.x, p0.y + q0.y, p0.z + q0.z, p0.w + q0.w,
                  p1.x + q1.x, p1.y + q1.y, p1.z + q1.z, p1.w + q1.w};
    float ss = 0.f;
#pragma unroll
    for (int j = 0; j < 8; ++j) ss += t[j] * t[j];
    ss = wave_sum(ss);
    __shared__ float sb[4];
    if ((tid & 63) == 0) sb[tid >> 6] = ss;
    __syncthreads();
    ss = sb[0] + sb[1] + sb[2] + sb[3];
    float rsq = 1.0f / sqrtf(ss * (1.0f / (float)D) + EPSV);
    float4 w0 = *(const float4*)(wpost + i0);
    float4 w1 = *(const float4*)(wpost + i0 + 4);
    float wv[8] = {w0.x, w0.y, w0.z, w0.w, w1.x, w1.y, w1.z, w1.w};
    float o[8];
#pragma unroll
    for (int j = 0; j < 8; ++j) o[j] = t[j] * rsq * wv[j];
    float4 r0 = {o[0], o[1], o[2], o[3]};
    float4 r1 = {o[4], o[5], o[6], o[7]};
    *(float4*)(x_dst + (size_t)row * D + i0) = r0;
    *(float4*)(x_dst + (size_t)row * D + i0 + 4) = r1;
    uint4 ob;
    ob.x = (uint)f2bf(o[0]) | ((uint)f2bf(o[1]) << 16);
    ob.y = (uint)f2bf(o[2]) | ((uint)f2bf(o[3]) << 16);
    ob.z = (uint)f2bf(o[4]) | ((uint)f2bf(o[5]) << 16);
    ob.w = (uint)f2bf(o[6]) | ((uint)f2bf(o[7]) << 16);
    *(uint4*)(xb + (size_t)row * D + i0) = ob;
}

// ---------------- attention v5: 1-wave blocks, 64-row tiles, 12KB LDS ----------------
// 4096 blocks -> ~13 resident/CU (LDS-limited), all sync is intra-wave waitcnt.
__global__ __launch_bounds__(64) void attn_kernel(
    const ushort* __restrict__ qb, const float* __restrict__ kv,
    ushort* __restrict__ ctxb) {
    __shared__ ushort qlds[64 * 64];    // 8 KB (q, then reused for ctx bounce)
    __shared__ ushort klds[16 * 64];    // 2 KB
    __shared__ ushort vlds[16 * 64];    // 2 KB
    int blk = blockIdx.x;
    int b  = blk >> 10;                 // 32 h * 32 ltiles = 1024 blocks per batch
    int h  = (blk >> 5) & 31;
    int l0 = (blk & 31) << 6;
    int tid = threadIdx.x;              // == lane (1 wave)
    // async-stage q tile (64 rows x 128B), pre-swizzled global source
    const ushort* qbase = qb + ((size_t)b * LSEQ + l0) * D + h * HDIM;
#pragma unroll
    for (int p = 0; p < 8; ++p) {
        int cb = p * 64;                // wave-uniform chunk base
        int ch = cb + tid;
        int r = ch >> 3;
        int c = (ch & 7) ^ (r & 7);
        gl_lds16(qbase + (size_t)r * D + c * 8, (void*)((char*)qlds + cb * 16));
    }
    // reg-stage K,V as bf16 (linear; compute reads are wave-uniform broadcasts)
    {
        int s = tid >> 2;
        int d0 = (tid & 3) * 16;
        const float* kp = kv + ((size_t)(b * NSLOT + s)) * (2 * D) + h * HDIM + d0;
        float4 k0 = *(const float4*)kp;
        float4 k1 = *(const float4*)(kp + 4);
        float4 k2 = *(const float4*)(kp + 8);
        float4 k3 = *(const float4*)(kp + 12);
        uint4 ka, kb2;
        ka.x = (uint)f2bf(k0.x) | ((uint)f2bf(k0.y) << 16);
        ka.y = (uint)f2bf(k0.z) | ((uint)f2bf(k0.w) << 16);
        ka.z = (uint)f2bf(k1.x) | ((uint)f2bf(k1.y) << 16);
        ka.w = (uint)f2bf(k1.z) | ((uint)f2bf(k1.w) << 16);
        kb2.x = (uint)f2bf(k2.x) | ((uint)f2bf(k2.y) << 16);
        kb2.y = (uint)f2bf(k2.z) | ((uint)f2bf(k2.w) << 16);
        kb2.z = (uint)f2bf(k3.x) | ((uint)f2bf(k3.y) << 16);
        kb2.w = (uint)f2bf(k3.z) | ((uint)f2bf(k3.w) << 16);
        *(uint4*)&klds[s * 64 + d0] = ka;
        *(uint4*)&klds[s * 64 + d0 + 8] = kb2;
        float4 v0 = *(const float4*)(kp + D);
        float4 v1 = *(const float4*)(kp + D + 4);
        float4 v2 = *(const float4*)(kp + D + 8);
        float4 v3 = *(const float4*)(kp + D + 12);
        uint4 va, vb;
        va.x = (uint)f2bf(v0.x) | ((uint)f2bf(v0.y) << 16);
        va.y = (uint)f2bf(v0.z) | ((uint)f2bf(v0.w) << 16);
        va.z = (uint)f2bf(v1.x) | ((uint)f2bf(v1.y) << 16);
        va.w = (uint)f2bf(v1.z) | ((uint)f2bf(v1.w) << 16);
        vb.x = (uint)f2bf(v2.x) | ((uint)f2bf(v2.y) << 16);
        vb.y = (uint)f2bf(v2.z) | ((uint)f2bf(v2.w) << 16);
        vb.z = (uint)f2bf(v3.x) | ((uint)f2bf(v3.y) << 16);
        vb.w = (uint)f2bf(v3.z) | ((uint)f2bf(v3.w) << 16);
        *(uint4*)&vlds[s * 64 + d0] = va;
        *(uint4*)&vlds[s * 64 + d0 + 8] = vb;
    }
    __syncthreads();                    // 1 wave: compiles to waitcnt (+barrier)
    int r = tid;                        // this thread's row (0..63)
    float acc[NSLOT];
#pragma unroll
    for (int s = 0; s < NSLOT; ++s) acc[s] = 0.f;
#pragma unroll
    for (int dc = 0; dc < 8; ++dc) {
        uint4 qc = *(const uint4*)&qlds[r * 64 + ((dc ^ (r & 7)) << 3)];
        float qf[8];
        qf[0] = __uint_as_float(qc.x << 16);
        qf[1] = __uint_as_float(qc.x & 0xffff0000u);
        qf[2] = __uint_as_float(qc.y << 16);
        qf[3] = __uint_as_float(qc.y & 0xffff0000u);
        qf[4] = __uint_as_float(qc.z << 16);
        qf[5] = __uint_as_float(qc.z & 0xffff0000u);
        qf[6] = __uint_as_float(qc.w << 16);
        qf[7] = __uint_as_float(qc.w & 0xffff0000u);
#pragma unroll
        for (int s = 0; s < NSLOT; ++s) {
            uint4 kc = *(const uint4*)&klds[s * 64 + dc * 8];   // broadcast
            float a = acc[s];
            a += qf[0] * __uint_as_float(kc.x << 16);
            a += qf[1] * __uint_as_float(kc.x & 0xffff0000u);
            a += qf[2] * __uint_as_float(kc.y << 16);
            a += qf[3] * __uint_as_float(kc.y & 0xffff0000u);
            a += qf[4] * __uint_as_float(kc.z << 16);
            a += qf[5] * __uint_as_float(kc.z & 0xffff0000u);
            a += qf[6] * __uint_as_float(kc.w << 16);
            a += qf[7] * __uint_as_float(kc.w & 0xffff0000u);
            acc[s] = a;
        }
    }
    float mx = acc[0];
#pragma unroll
    for (int s = 1; s < NSLOT; ++s) mx = fmaxf(mx, acc[s]);
    float e[NSLOT], den = 0.f;
#pragma unroll
    for (int s = 0; s < NSLOT; ++s) { e[s] = __expf((acc[s] - mx) * 0.125f); den += e[s]; }
    float inv = 1.0f / den;
#pragma unroll
    for (int s = 0; s < NSLOT; ++s) e[s] *= inv;
    // PV: bounce own-row ctx bf16 into qlds (swizzled -> conflict-free)
#pragma unroll
    for (int dc = 0; dc < 8; ++dc) {
        float cx[8] = {0.f, 0.f, 0.f, 0.f, 0.f, 0.f, 0.f, 0.f};
#pragma unroll
        for (int s = 0; s < NSLOT; ++s) {
            uint4 vc = *(const uint4*)&vlds[s * 64 + dc * 8];   // broadcast
            float es = e[s];
            cx[0] += es * __uint_as_float(vc.x << 16);
            cx[1] += es * __uint_as_float(vc.x & 0xffff0000u);
            cx[2] += es * __uint_as_float(vc.y << 16);
            cx[3] += es * __uint_as_float(vc.y & 0xffff0000u);
            cx[4] += es * __uint_as_float(vc.z << 16);
            cx[5] += es * __uint_as_float(vc.z & 0xffff0000u);
            cx[6] += es * __uint_as_float(vc.w << 16);
            cx[7] += es * __uint_as_float(vc.w & 0xffff0000u);
        }
        uint4 o;
        o.x = (uint)f2bf(cx[0]) | ((uint)f2bf(cx[1]) << 16);
        o.y = (uint)f2bf(cx[2]) | ((uint)f2bf(cx[3]) << 16);
        o.z = (uint)f2bf(cx[4]) | ((uint)f2bf(cx[5]) << 16);
        o.w = (uint)f2bf(cx[6]) | ((uint)f2bf(cx[7]) << 16);
        *(uint4*)&qlds[r * 64 + ((dc ^ (r & 7)) << 3)] = o;
    }
    __syncthreads();
    // cooperative coalesced global write: 8 rows x 128B per iter (full lines)
    ushort* cbase = ctxb + ((size_t)b * LSEQ + l0) * D + h * HDIM;
#pragma unroll
    for (int p = 0; p < 8; ++p) {
        int cid = p * 64 + tid;
        int row = cid >> 3;
        int c = cid & 7;
        *(uint4*)(cbase + (size_t)row * D + c * 8) =
            *(const uint4*)&qlds[row * 64 + ((c ^ (row & 7)) << 3)];
    }
}

// ---------------- small-M bf16 MFMA GEMM (M<=128 rows) ----------------
template <int BM>
__global__ __launch_bounds__(256) void gemm_bt(
    const ushort* __restrict__ A, const ushort* __restrict__ Bw,
    const float* __restrict__ bias, float* __restrict__ C,
    int M, int N, int K) {
    constexpr int BN = 128, BK = 32;
    constexpr int MF = BM / 32;
    constexpr int APASS = (BM * BK / 8) / 256;
    __shared__ short lds[2][(BM + BN) * BK];
    int tid = threadIdx.x;
    int lane = tid & 63, w = tid >> 6;
    int wr = w >> 1, wc = w & 1;
    int tn = blockIdx.x * BN;
    int tm = blockIdx.y * BM;
    f32x4 acc[MF][4];
    f32x4 zero = {0.f, 0.f, 0.f, 0.f};
#pragma unroll
    for (int m = 0; m < MF; ++m)
#pragma unroll
        for (int n = 0; n < 4; ++n) acc[m][n] = zero;
    int NT = K / BK;

    auto stage = [&](int buf, int t) {
        int kt = t * BK;
#pragma unroll
        for (int p = 0; p < APASS; ++p) {
            int cb = p * 256 + w * 64;
            int c = cb + lane;
            int r = c >> 2;
            int k8 = (c & 3) * 8;
            int gr = tm + r;
            if (gr >= M) gr = M - 1;
            gl_lds16(A + (size_t)gr * K + kt + k8, (void*)&lds[buf][cb * 8]);
        }
#pragma unroll
        for (int p = 0; p < 2; ++p) {
            int cb = p * 256 + w * 64;
            int c = cb + lane;
            int r = c >> 2;
            int k8 = (c & 3) * 8;
            gl_lds16(Bw + (size_t)(tn + r) * K + kt + k8,
                     (void*)&lds[buf][BM * BK + cb * 8]);
        }
    };
    stage(0, 0);
    for (int t = 0; t < NT; ++t) {
        __syncthreads();
        if (t + 1 < NT) stage((t + 1) & 1, t + 1);
        const short* Ab = &lds[t & 1][0];
        const short* Bb = &lds[t & 1][BM * BK];
        int ko = (lane >> 4) * 8;
        int rr = lane & 15;
        bf16x8 af[MF], bfr[4];
#pragma unroll
        for (int m = 0; m < MF; ++m)
            af[m] = *(const bf16x8*)&Ab[(wr * (MF * 16) + m * 16 + rr) * BK + ko];
#pragma unroll
        for (int n = 0; n < 4; ++n)
            bfr[n] = *(const bf16x8*)&Bb[(wc * 64 + n * 16 + rr) * BK + ko];
#pragma unroll
        for (int m = 0; m < MF; ++m)
#pragma unroll
            for (int n = 0; n < 4; ++n)
                acc[m][n] = __builtin_amdgcn_mfma_f32_16x16x32_bf16(af[m], bfr[n],
                                                                    acc[m][n], 0, 0, 0);
    }
#pragma unroll
    for (int m = 0; m < MF; ++m) {
#pragma unroll
        for (int n = 0; n < 4; ++n) {
            int col = tn + wc * 64 + n * 16 + (lane & 15);
            float bsv = bias ? bias[col] : 0.f;
#pragma unroll
            for (int r = 0; r < 4; ++r) {
                int rowi = tm + wr * (MF * 16) + m * 16 + (lane >> 4) * 4 + r;
                if (rowi < M) C[(size_t)rowi * N + col] = acc[m][n][r] + bsv;
            }
        }
    }
}

// ---------------- big GEMM: 256x256 tile, BK=64, 8 waves, counted vmcnt ----------------
template <typename OT>
__global__ __launch_bounds__(512, 2) void gemm_big(
    const ushort* __restrict__ A, const ushort* __restrict__ Bw,
    const float* __restrict__ bias, OT* __restrict__ C,
    int M, int N, int K) {
    __shared__ ushort Al[2][256 * 64];   // 64 KiB
    __shared__ ushort Bl[2][256 * 64];   // 64 KiB
    int blk = blockIdx.x;
    int bn = blk & 7;                    // same-XCD blocks share B panel (L2)
    int bm = blk >> 3;
    int tid = threadIdx.x;
    int lane = tid & 63, wv = tid >> 6;
    int wm = wv >> 2, wn = wv & 3;       // 2 x 4 wave grid -> 128x64 per wave
    int rr = lane & 15, ko = lane >> 4;  // frag row, k-octet 0..3
    const size_t rowA0 = (size_t)bm * 256;
    const size_t rowB0 = (size_t)bn * 256;

    auto stage = [&](int buf, int t) {
        int kt = t * 64;
#pragma unroll
        for (int p = 0; p < 4; ++p) {
            int cb = p * 512 + wv * 64;          // wave-uniform chunk base
            int ch = cb + lane;
            int r = ch >> 3;
            int cl = (ch & 7) ^ (r & 7);         // pre-swizzled source chunk
            gl_lds16(A + (rowA0 + r) * K + kt + cl * 8,
                     (void*)((char*)&Al[buf][0] + cb * 16));
        }
#pragma unroll
        for (int p = 0; p < 4; ++p) {
            int cb = p * 512 + wv * 64;
            int ch = cb + lane;
            int r = ch >> 3;
            int cl = (ch & 7) ^ (r & 7);
            gl_lds16(Bw + (rowB0 + r) * K + kt + cl * 8,
                     (void*)((char*)&Bl[buf][0] + cb * 16));
        }
    };

    f32x4 acc[8][4];
    f32x4 zero = {0.f, 0.f, 0.f, 0.f};
#pragma unroll
    for (int m = 0; m < 8; ++m)
#pragma unroll
        for (int n = 0; n < 4; ++n) acc[m][n] = zero;

    int NT = K / 64;
    stage(0, 0);
    stage(1, 1);
    for (int t = 0; t < NT; ++t) {
        // wait for THIS tile's 8 loads (t+1's 8 may stay in flight)
        if (t + 2 <= NT) asm volatile("s_waitcnt vmcnt(8)" ::: "memory");
        else             asm volatile("s_waitcnt vmcnt(0)" ::: "memory");
        asm volatile("s_barrier" ::: "memory");   // all waves' tile-t loads landed
        const ushort* Ab = &Al[t & 1][0];
        const ushort* Bb = &Bl[t & 1][0];
        bf16x8 bfr[4][2];
#pragma unroll
        for (int n = 0; n < 4; ++n)
#pragma unroll
            for (int ks = 0; ks < 2; ++ks) {
                int r = wn * 64 + n * 16 + rr;
                int cl = ks * 4 + ko;
                bfr[n][ks] = *(const bf16x8*)((const char*)Bb + r * 128 +
                                              ((cl ^ (r & 7)) * 16));
            }
        __builtin_amdgcn_s_setprio(1);
#pragma unroll
        for (int m = 0; m < 8; ++m) {
            int r = wm * 128 + m * 16 + rr;
            bf16x8 a0 = *(const bf16x8*)((const char*)Ab + r * 128 +
                                         (((0 + ko) ^ (r & 7)) * 16));
            bf16x8 a1 = *(const bf16x8*)((const char*)Ab + r * 128 +
                                         (((4 + ko) ^ (r & 7)) * 16));
#pragma unroll
            for (int n = 0; n < 4; ++n) {
                acc[m][n] = __builtin_amdgcn_mfma_f32_16x16x32_bf16(a0, bfr[n][0],
                                                                    acc[m][n], 0, 0, 0);
                acc[m][n] = __builtin_amdgcn_mfma_f32_16x16x32_bf16(a1, bfr[n][1],
                                                                    acc[m][n], 0, 0, 0);
            }
        }
        __builtin_amdgcn_s_setprio(0);
        asm volatile("s_barrier" ::: "memory");   // all waves done reading buf[t&1]
        if (t + 2 < NT) stage(t & 1, t + 2);      // overwrite just-consumed buffer
    }
    int crow0 = (int)rowA0 + wm * 128;
    int ccol0 = bn * 256 + wn * 64;
#pragma unroll
    for (int m = 0; m < 8; ++m)
#pragma unroll
        for (int n = 0; n < 4; ++n) {
            int col = ccol0 + n * 16 + rr;
            float bsv = bias ? bias[col] : 0.f;
#pragma unroll
            for (int r4 = 0; r4 < 4; ++r4) {
                int row = crow0 + m * 16 + ko * 4 + r4;
                float v = acc[m][n][r4] + bsv;
                if constexpr (sizeof(OT) == 2) {
                    ((ushort*)C)[(size_t)row * N + col] = f2bf(v);
                } else {
                    ((float*)C)[(size_t)row * N + col] = v;
                }
            }
        }
}

extern "C" void kernel_launch(void* const* d_in, const int* in_sizes, int n_in,
                              void* d_out, int out_size, void* d_ws, size_t ws_size,
                              hipStream_t stream) {
    const float* x_in       = (const float*)d_in[0];
    const float* workspace  = (const float*)d_in[1];
    const float* compete_w  = (const float*)d_in[2];
    const float* compete_b  = (const float*)d_in[3];
    const float* write_w    = (const float*)d_in[4];
    const float* write_b    = (const float*)d_in[5];
    const float* in_proj_w  = (const float*)d_in[6];
    const float* in_proj_b  = (const float*)d_in[7];
    const float* out_proj_w = (const float*)d_in[8];
    const float* out_proj_b = (const float*)d_in[9];
    const float* norm_pre_w  = (const float*)d_in[12];
    const float* norm_post_w = (const float*)d_in[13];
    float* xout = (float*)d_out;

    char* base = (char*)d_ws;
    size_t off = 0;
    auto alloc = [&](size_t bytes) {
        void* p = base + off;
        off += (bytes + 255) & ~(size_t)255;
        return p;
    };
    ushort* xb      = (ushort*)alloc((size_t)BL * D * 2);
    float*  qbuf    = (float*) alloc((size_t)BL * D * 4);     // attn_out (f32)
    ushort* qbb     = (ushort*)alloc((size_t)BL * D * 2);     // q bf16
    ushort* ctxb    = (ushort*)alloc((size_t)BL * D * 2);
    float*  logits  = (float*) alloc((size_t)BATCH * NSLOT * LSEQ * 4);
    ushort* xbar    = (ushort*)alloc((size_t)BATCH * NSLOT * D * 2);
    float*  written = (float*) alloc((size_t)BATCH * NSLOT * D * 4);
    float*  wsbuf   = (float*) alloc((size_t)BATCH * NSLOT * D * 4);
    ushort* wsb     = (ushort*)alloc((size_t)BATCH * NSLOT * D * 2);
    float*  kvbuf   = (float*) alloc((size_t)BATCH * NSLOT * 2 * D * 4);
    ushort* ipb     = (ushort*)alloc((size_t)3 * D * D * 2);
    ushort* wob     = (ushort*)alloc((size_t)D * D * 2);
    ushort* wwb     = (ushort*)alloc((size_t)D * D * 2);
    (void)ws_size; (void)in_sizes; (void)n_in; (void)out_size;

    conv_bf16_kernel<<<2048, 256, 0, stream>>>((const float4*)in_proj_w, ipb, 3 * D * D / 4);
    conv_bf16_kernel<<<2048, 256, 0, stream>>>((const float4*)out_proj_w, wob, D * D / 4);
    conv_bf16_kernel<<<2048, 256, 0, stream>>>((const float4*)write_w, wwb, D * D / 4);
    conv_bf16_kernel<<<2048, 256, 0, stream>>>((const float4*)x_in, xb, BL * D / 4);

    for (int it = 0; it < 2; ++it) {
        const float* xs = it ? (const float*)xout : x_in;
        logits_kernel<<<BL / 4, 256, 0, stream>>>(xs, compete_w, compete_b, norm_pre_w,
                                                  logits);
        topk_xbar_kernel<<<BATCH * NSLOT, 256, 0, stream>>>(logits, xs, xbar);
        gemm_bt<64><<<dim3(D / 128, 1), 256, 0, stream>>>(xbar, wwb, write_b, written,
                                                          BATCH * NSLOT, D, D);
        ws_update_kernel<<<BATCH * NSLOT, 256, 0, stream>>>(written, wsbuf, workspace,
                                                            it == 0 ? 1 : 0, norm_post_w,
                                                            wsbuf, wsb);
        gemm_bt<64><<<dim3(2 * D / 128, 1), 256, 0, stream>>>(wsb, ipb + (size_t)D * D,
                                                              in_proj_b + D, kvbuf,
                                                              BATCH * NSLOT, 2 * D, D);
        gemm_big<ushort><<<(D / 256) * (BL / 256), 512, 0, stream>>>(xb, ipb, in_proj_b,
                                                                     qbb, BL, D, D);
        attn_kernel<<<BATCH * NHEAD * (LSEQ / 64), 64, 0, stream>>>(qbb, kvbuf, ctxb);
        gemm_big<float><<<(D / 256) * (BL / 256), 512, 0, stream>>>(ctxb, wob, out_proj_b,
                                                                    qbuf, BL, D, D);
        resid_rms_kernel<<<BL, 256, 0, stream>>>(xs, qbuf, norm_post_w, xout, xb);
    }
}